// Round 1
// baseline (35.472 us; speedup 1.0000x reference)
//
#include <hip/hip_runtime.h>
#include <hip/hip_bf16.h>

// Problem constants (match reference setup_inputs)
constexpr int B       = 64;
constexpr int S       = 4096;
constexpr int D       = 128;
constexpr int NC      = 64;    // N_CELLS
constexpr int DTH     = 63;    // d_theta = NC - 1
constexpr int NSTEPS  = 50;
constexpr int SPLIT   = 16;    // S-chunks per batch for the reduction
constexpr int SC      = S / SPLIT;  // 256 rows per chunk

// ---------------------------------------------------------------------------
// Stage 1: partial column sums of input_seq over S.
//   in   : (B, S, D) f32
//   part : (B*SPLIT, D) f32   (lives in d_out, overwritten later by stage 3)
// Block: 256 threads, one (batch, chunk) per block. float4 loads, coalesced.
// ---------------------------------------------------------------------------
__global__ __launch_bounds__(256) void cpab_reduce(const float* __restrict__ in,
                                                   float* __restrict__ part) {
    const int blk   = blockIdx.x;          // 0 .. B*SPLIT-1
    const int b     = blk / SPLIT;
    const int chunk = blk % SPLIT;
    const int t     = threadIdx.x;         // 0..255
    const int d4    = t & 31;              // which float4 of the 32 per row
    const int srow  = t >> 5;              // 0..7

    const float4* base = reinterpret_cast<const float4*>(
        in + (size_t)b * S * D + (size_t)chunk * SC * D);

    float4 acc = make_float4(0.f, 0.f, 0.f, 0.f);
    for (int s = srow; s < SC; s += 8) {
        float4 v = base[s * 32 + d4];
        acc.x += v.x; acc.y += v.y; acc.z += v.z; acc.w += v.w;
    }

    __shared__ float4 sm[256];
    sm[t] = acc;
    __syncthreads();

    if (t < 32) {
        float4 a = sm[t];
        #pragma unroll
        for (int r = 1; r < 8; ++r) {
            float4 v = sm[r * 32 + t];
            a.x += v.x; a.y += v.y; a.z += v.z; a.w += v.w;
        }
        reinterpret_cast<float4*>(part + (size_t)(b * SPLIT + chunk) * D)[d4] = a;
    }
}

// ---------------------------------------------------------------------------
// Stage 2: fold partials -> mean -> theta -> A = theta @ basis^T
//   part  : (B*SPLIT, D)
//   W     : (D, DTH) row-major
//   bloc  : (DTH,)
//   basis : (2*NC, DTH) row-major
//   Aout  : (B, 128)   A[b, 2c] = a_cell, A[b, 2c+1] = b_cell  (in d_ws)
// One block per batch, 128 threads.
// ---------------------------------------------------------------------------
__global__ __launch_bounds__(128) void cpab_theta(const float* __restrict__ part,
                                                  const float* __restrict__ W,
                                                  const float* __restrict__ bloc,
                                                  const float* __restrict__ basis,
                                                  float* __restrict__ Aout) {
    const int b = blockIdx.x;   // 0..B-1
    const int t = threadIdx.x;  // 0..127

    __shared__ float s_mean[D];
    __shared__ float s_theta[DTH];

    float tot = 0.f;
    #pragma unroll
    for (int c = 0; c < SPLIT; ++c)
        tot += part[(size_t)(b * SPLIT + c) * D + t];
    s_mean[t] = tot * (1.0f / (float)S);
    __syncthreads();

    if (t < DTH) {
        float th = bloc[t];
        for (int d = 0; d < D; ++d)
            th += s_mean[d] * W[d * DTH + t];
        s_theta[t] = th;
    }
    __syncthreads();

    float acc = 0.f;
    for (int j = 0; j < DTH; ++j)
        acc += s_theta[j] * basis[t * DTH + j];
    Aout[b * 128 + t] = acc;
}

// ---------------------------------------------------------------------------
// Stage 3: CPAB warp — 50 Euler steps per grid point.
//   Aab : (B, 128) cell coefficients
//   out : (B, S)
// One block per 256 consecutive grid points of one batch.
// ---------------------------------------------------------------------------
__global__ __launch_bounds__(256) void cpab_warp(const float* __restrict__ Aab,
                                                 float* __restrict__ out) {
    const int blk   = blockIdx.x;          // B * (S/256)
    const int b     = blk >> 4;            // / (S/256 == 16)
    const int chunk = blk & 15;
    const int t     = threadIdx.x;

    __shared__ float ab[128];
    if (t < 128) ab[t] = Aab[b * 128 + t];
    __syncthreads();

    const int s = chunk * 256 + t;
    float x = (float)s * (1.0f / (float)(S - 1));
    const float dt = 1.0f / (float)NSTEPS;

    #pragma unroll
    for (int it = 0; it < NSTEPS; ++it) {
        int c = (int)(x * (float)NC);          // trunc toward zero == astype(int32)
        c = c < 0 ? 0 : (c > NC - 1 ? NC - 1 : c);
        float a  = ab[2 * c];
        float bb = ab[2 * c + 1];
        x = x + (a * x + bb) * dt;
    }

    out[(size_t)b * S + s] = x;
}

extern "C" void kernel_launch(void* const* d_in, const int* in_sizes, int n_in,
                              void* d_out, int out_size, void* d_ws, size_t ws_size,
                              hipStream_t stream) {
    const float* in_seq = (const float*)d_in[0];  // (B, S, D)
    const float* W_loc  = (const float*)d_in[1];  // (D, DTH)
    const float* b_loc  = (const float*)d_in[2];  // (DTH,)
    const float* basis  = (const float*)d_in[3];  // (2*NC, DTH)
    float*       out    = (float*)d_out;          // (B, S)

    // Scratch layout:
    //   partials (B*SPLIT*D = 131072 floats) -> reuse d_out (262144 floats),
    //     consumed by stage 2 before stage 3 overwrites d_out.
    //   A coefficients (B*128 = 8192 floats) -> d_ws (32 KiB).
    float* part = out;
    float* Aab  = (float*)d_ws;

    cpab_reduce<<<B * SPLIT, 256, 0, stream>>>(in_seq, part);
    cpab_theta<<<B, 128, 0, stream>>>(part, W_loc, b_loc, basis, Aab);
    cpab_warp<<<B * (S / 256), 256, 0, stream>>>(Aab, out);
}